// Round 7
// baseline (277.895 us; speedup 1.0000x reference)
//
#include <hip/hip_runtime.h>

// Encoding layer. B=16, C=512, N=4096, K=32.
// v8: reduce-style mega-burst staging. Evidence: reduce_kernel (this file)
// streams 5.3 TB/s with 4 waves/CU because each thread has 32 independent
// loads in flight and NO drain points; every enc variant kept <=8KB/wave in
// flight drained once per 64-c group and delivered ~2.1 TB/s. Changes:
//  - staging = 2 bursts x 16 independent float4/thread (256 B/lane in
//    flight), each drained exactly once. Burst A (c 0..255) -> LDS ->
//    GEMM1a (waves 0,1) while burst B (c 256..511) flies in registers.
//  - single half-tile XC (35 KB) reused for both halves; total LDS ~52 KB
//    -> 3 blocks/CU resident; grid 1024 (CHUNK=64, 4 rounds/CU).
//  - GEMM1 split by c-half across wave pairs; S merged via 8 KB LDS stash;
//    softmax lane-local (v5); 5 lgkm-only barriers total.
//  - GEMM2: v0's proven global register ring (L3-hot), 16 steps 6-deep.
//  - partials 1024 x 64 KB = 64 MiB -> reduce kernel.

#define B_ 16
#define C_ 512
#define N_ 4096
#define K_ 32
#define CHUNK 64                  // tokens per block
#define NCH (N_ / CHUNK)          // 64 chunks per batch
#define NBLK (B_ * NCH)           // 1024 blocks
#define XCN 68                    // XC n-stride (u16): 136 B (8B-aligned rows)
#define WLS 40                    // Wl n-stride (u16): 80 B

typedef __attribute__((ext_vector_type(8))) short short8;
typedef __attribute__((ext_vector_type(16))) float floatx16;

__device__ inline unsigned short f2bf(float f) {
    union { float f; unsigned u; } v; v.f = f;
    unsigned r = v.u + 0x7FFFu + ((v.u >> 16) & 1u);  // RNE
    return (unsigned short)(r >> 16);
}

// LDS-drain-only barrier: global loads (vmcnt) stay in flight across it.
__device__ inline void cbar() {
    __builtin_amdgcn_sched_barrier(0);
    asm volatile("s_waitcnt lgkmcnt(0)" ::: "memory");
    __builtin_amdgcn_s_barrier();
    __builtin_amdgcn_sched_barrier(0);
}

template <int USE_WS>
__global__ __launch_bounds__(256, 3)
void enc_kernel(const float* __restrict__ x,
                const float* __restrict__ cw,
                const float* __restrict__ scale,
                float* __restrict__ outp)
{
    __shared__ unsigned short XC[256 * XCN];     // one c-half bf16 [row][n], 34816 B
    __shared__ float Sp[2][K_ * 32];             // half-1 S partials, 8192 B
    __shared__ float xsqL[16][CHUNK];            // ||x_n||^2 partials by r, 4096 B
    __shared__ unsigned short Wl[2][K_ * WLS];   // softmax w bf16 [tile][k][n], 5120 B
    __shared__ float csq[K_];
    __shared__ float scl[K_];

    const int tid  = threadIdx.x;
    const int wave = tid >> 6;
    const int lane = tid & 63;
    const int l31  = lane & 31;
    const int lh   = lane >> 5;
    const int half = wave >> 1;                  // c-half owned in GEMM1
    const int tile = wave & 1;                   // token-tile owned in GEMM1

    const int b     = blockIdx.x >> 6;           // NCH = 64
    const int chunk = blockIdx.x & (NCH - 1);
    const float* xb = x + (long)b * C_ * N_;

    // staging mapping: thread = (r = tid>>4, p = tid&15); per burst it loads
    // 16 rows (local row = i*16 + r), each one float4 (tokens p*4..p*4+3).
    const int r = tid >> 4;
    const int p = tid & 15;
    const float* xrow = xb + chunk * CHUNK + p * 4;

    float4 bufA[16], bufB[16];
#define BISSUE(buf_, cbase_)                                                   \
    { _Pragma("unroll")                                                        \
      for (int i = 0; i < 16; ++i)                                             \
          buf_[i] = *(const float4*)(xrow + (long)((cbase_) + i * 16 + r) * N_); }

    float xs0 = 0.f, xs1 = 0.f, xs2 = 0.f, xs3 = 0.f;
#define BWRITE(buf_)                                                           \
    { _Pragma("unroll")                                                        \
      for (int i = 0; i < 16; ++i) {                                           \
          const float4 v = buf_[i];                                            \
          xs0 += v.x * v.x; xs1 += v.y * v.y;                                  \
          xs2 += v.z * v.z; xs3 += v.w * v.w;                                  \
          const unsigned lo = (unsigned)f2bf(v.x) | ((unsigned)f2bf(v.y) << 16);\
          const unsigned hi = (unsigned)f2bf(v.z) | ((unsigned)f2bf(v.w) << 16);\
          *(uint2*)&XC[(i * 16 + r) * XCN + p * 4] = make_uint2(lo, hi);       \
      } }

    // GEMM1 A-fragments: f32 cw rows (L2-hot) converted in-register.
    const float* cwr = cw + l31 * C_ + lh * 8;
    short8 afA[4], afB[4];
#define AFLOADG(buf_, coff_)                                                   \
    { _Pragma("unroll")                                                        \
      for (int s = 0; s < 4; ++s) {                                            \
          const float4 u0 = *(const float4*)(cwr + (coff_) + s * 16);          \
          const float4 u1 = *(const float4*)(cwr + (coff_) + s * 16 + 4);      \
          short8 t_;                                                           \
          t_[0] = (short)f2bf(u0.x); t_[1] = (short)f2bf(u0.y);                \
          t_[2] = (short)f2bf(u0.z); t_[3] = (short)f2bf(u0.w);                \
          t_[4] = (short)f2bf(u1.x); t_[5] = (short)f2bf(u1.y);                \
          t_[6] = (short)f2bf(u1.z); t_[7] = (short)f2bf(u1.w);                \
          buf_[s] = t_; } }

    // one local group (64 c) of MFMA off the XC half-tile
#define G1STEP(afbuf_, lg_)                                                    \
    { _Pragma("unroll")                                                        \
      for (int s = 0; s < 4; ++s) {                                            \
          short8 bx;                                                           \
          _Pragma("unroll")                                                    \
          for (int j = 0; j < 8; ++j)                                          \
              bx[j] = (short)XC[((lg_) * 64 + s * 16 + lh * 8 + j) * XCN       \
                                + tile * 32 + l31];                            \
          S = __builtin_amdgcn_mfma_f32_32x32x16_bf16(afbuf_[s], bx, S, 0, 0, 0);\
      } }

    // ---- prologue: burst A first, VALU work under its latency ----
    BISSUE(bufA, 0)
    if (tid < K_) scl[tid] = scale[tid];
    {
        const int k = tid >> 3, q = tid & 7;      // k row, 64-c slice
        const float4* src = (const float4*)(cw + k * C_ + q * 64);
        float ssum = 0.f;
        #pragma unroll
        for (int i = 0; i < 16; ++i) {
            const float4 v = src[i];
            ssum += v.x*v.x + v.y*v.y + v.z*v.z + v.w*v.w;
        }
        ssum += __shfl_xor(ssum, 1);
        ssum += __shfl_xor(ssum, 2);
        ssum += __shfl_xor(ssum, 4);
        if (q == 0) csq[k] = ssum;
    }
    AFLOADG(afA, half * 256)       // first group of my c-half

    BWRITE(bufA)                   // drains burst A (progressive vmcnt)
    BISSUE(bufB, 256)              // burst B flies through GEMM1a
    cbar();                        // XC = c 0..255

    floatx16 S;
    #pragma unroll
    for (int i = 0; i < 16; ++i) S[i] = 0.f;

    // ---- GEMM1a: waves 0,1 (half 0) on c 0..255 ----
    if (half == 0) {
        AFLOADG(afB, 64)
        G1STEP(afA, 0)
        AFLOADG(afA, 128)
        G1STEP(afB, 1)
        AFLOADG(afB, 192)
        G1STEP(afA, 2)
        G1STEP(afB, 3)
    }
    cbar();                        // half-0 XC reads done

    BWRITE(bufB)                   // XC rows now c 256..511
    xsqL[r][p * 4 + 0] = xs0; xsqL[r][p * 4 + 1] = xs1;
    xsqL[r][p * 4 + 2] = xs2; xsqL[r][p * 4 + 3] = xs3;
    cbar();                        // XC half-B + xsqL ready

    // ---- GEMM1b: waves 2,3 (half 1) on c 256..511; write S partials ----
    if (half == 1) {
        AFLOADG(afB, 256 + 64)
        G1STEP(afA, 0)
        AFLOADG(afA, 256 + 128)
        G1STEP(afB, 1)
        AFLOADG(afB, 256 + 192)
        G1STEP(afA, 2)
        G1STEP(afB, 3)
        #pragma unroll
        for (int rr = 0; rr < 16; ++rr)
            Sp[tile][((rr & 3) + 8 * (rr >> 2) + 4 * lh) * 32 + l31] = S[rr];
    }

    // ---- GEMM2 ring prefetch (6-deep, L3-hot; survives lgkm barriers) ----
    float4 bv[6][2];
#define G2LOAD(bi_, i_)                                                        \
    { const int t_ = (i_) >> 2, st_ = (i_) & 3;                                \
      const int c_ = wave * 128 + t_ * 32 + l31;                               \
      const int no_ = st_ * 16 + lh * 8;                                       \
      const float* p_ = xb + (long)c_ * N_ + chunk * CHUNK + no_;              \
      bv[bi_][0] = *(const float4*)p_;                                         \
      bv[bi_][1] = *(const float4*)(p_ + 4); }
    if (half == 0) {
        G2LOAD(0, 0) G2LOAD(1, 1) G2LOAD(2, 2)
        G2LOAD(3, 3) G2LOAD(4, 4) G2LOAD(5, 5)
    }
    cbar();                        // Sp ready

    // ---- softmax (waves 0,1): token n = tile*32+l31; lane pair = 16 k's ----
    if (half == 0) {
        const int n = tile * 32 + l31;
        float xq = 0.f;
        #pragma unroll
        for (int rr = 0; rr < 16; ++rr) xq += xsqL[rr][n];
        float L[16], mx = -3.4e38f;
        #pragma unroll
        for (int rr = 0; rr < 16; ++rr) {
            const int k = (rr & 3) + 8 * (rr >> 2) + 4 * lh;
            L[rr] = scl[k] * (xq - 2.f * (S[rr] + Sp[tile][k * 32 + l31]) + csq[k]);
            mx = fmaxf(mx, L[rr]);
        }
        mx = fmaxf(mx, __shfl_xor(mx, 32));
        float sum = 0.f;
        #pragma unroll
        for (int rr = 0; rr < 16; ++rr) { L[rr] = __expf(L[rr] - mx); sum += L[rr]; }
        sum += __shfl_xor(sum, 32);
        const float inv = 1.f / sum;
        #pragma unroll
        for (int rr = 0; rr < 16; ++rr) {
            const int k = (rr & 3) + 8 * (rr >> 2) + 4 * lh;
            Wl[tile][k * WLS + l31] = f2bf(L[rr] * inv);
        }
    } else {
        G2LOAD(0, 0) G2LOAD(1, 1) G2LOAD(2, 2)    // half-1 ring under softmax
        G2LOAD(3, 3) G2LOAD(4, 4) G2LOAD(5, 5)
    }
    cbar();                        // Wl handoff

    // ========== GEMM2: enc[k][c] = sum_n W[k][n] x[n][c] ==========
    short8 aw[4];
    #pragma unroll
    for (int st = 0; st < 4; ++st)
        aw[st] = *(const short8*)&Wl[st >> 1][l31 * WLS + (st & 1) * 16 + lh * 8];

    floatx16 wacc;
    #pragma unroll
    for (int i = 0; i < 16; ++i) wacc[i] = 0.f;
    {
        short8 ones;
        #pragma unroll
        for (int j = 0; j < 8; ++j) ones[j] = (short)0x3F80;
        #pragma unroll
        for (int st = 0; st < 4; ++st)
            wacc = __builtin_amdgcn_mfma_f32_32x32x16_bf16(aw[st], ones, wacc, 0, 0, 0);
    }

    floatx16 acc[4];
    #pragma unroll
    for (int t = 0; t < 4; ++t)
        #pragma unroll
        for (int i = 0; i < 16; ++i) acc[t][i] = 0.f;

    #pragma unroll
    for (int i = 0; i < 16; ++i) {               // i = t*4 + st
        const int bi = i % 6;
        const int t  = i >> 2, st = i & 3;
        const float4 v0 = bv[bi][0];
        const float4 v1 = bv[bi][1];
        short8 bx;
        bx[0] = (short)f2bf(v0.x); bx[1] = (short)f2bf(v0.y);
        bx[2] = (short)f2bf(v0.z); bx[3] = (short)f2bf(v0.w);
        bx[4] = (short)f2bf(v1.x); bx[5] = (short)f2bf(v1.y);
        bx[6] = (short)f2bf(v1.z); bx[7] = (short)f2bf(v1.w);
        acc[t] = __builtin_amdgcn_mfma_f32_32x32x16_bf16(aw[st], bx, acc[t], 0, 0, 0);
        if (i + 6 < 16) G2LOAD(bi, i + 6)
    }

    // ---- epilogue: val = acc - wsum[k]*cw[k][c] (f32 cw) ----
    float* dst = USE_WS ? (outp + (size_t)blockIdx.x * K_ * C_)
                        : (outp + (size_t)b * K_ * C_);
    #pragma unroll
    for (int t = 0; t < 4; ++t) {
        const int c = wave * 128 + t * 32 + l31;
        #pragma unroll
        for (int rr = 0; rr < 16; ++rr) {
            const int k = (rr & 3) + 8 * (rr >> 2) + 4 * lh;
            const float val = acc[t][rr] - wacc[rr] * cw[k * C_ + c];
            if (USE_WS) dst[k * C_ + c] = val;
            else        atomicAdd(dst + k * C_ + c, val);
        }
    }
}

// out[b][k][c] = sum_{ch<64} part[b*64+ch][k][c];  grid 256 x 256, float4
__global__ __launch_bounds__(256)
void reduce_kernel(const float4* __restrict__ part, float4* __restrict__ out)
{
    const int gid = blockIdx.x * 256 + threadIdx.x;   // 0..65535
    const int bb  = gid >> 12;                        // 4096 float4 per batch
    const int i4  = gid & 4095;
    const float4* pp = part + ((size_t)bb * NCH) * 4096 + i4;
    float4 s = make_float4(0.f, 0.f, 0.f, 0.f);
    #pragma unroll 32
    for (int j = 0; j < NCH; ++j) {
        const float4 v = pp[(size_t)j * 4096];
        s.x += v.x; s.y += v.y; s.z += v.z; s.w += v.w;
    }
    out[gid] = s;
}

extern "C" void kernel_launch(void* const* d_in, const int* in_sizes, int n_in,
                              void* d_out, int out_size, void* d_ws, size_t ws_size,
                              hipStream_t stream) {
    const float* x     = (const float*)d_in[0];
    const float* cw    = (const float*)d_in[1];
    const float* scale = (const float*)d_in[2];
    float* out = (float*)d_out;

    const size_t ws_need = (size_t)NBLK * K_ * C_ * sizeof(float);  // 64 MiB
    if (ws_size >= ws_need) {
        float* part = (float*)d_ws;
        hipLaunchKernelGGL(enc_kernel<1>, dim3(NBLK), dim3(256), 0, stream,
                           x, cw, scale, part);
        hipLaunchKernelGGL(reduce_kernel, dim3(256), dim3(256), 0, stream,
                           (const float4*)part, (float4*)out);
    } else {
        hipMemsetAsync(out, 0, (size_t)out_size * sizeof(float), stream);
        hipLaunchKernelGGL(enc_kernel<0>, dim3(NBLK), dim3(256), 0, stream,
                           x, cw, scale, out);
    }
}

// Round 8
// 241.374 us; speedup vs baseline: 1.1513x; 1.1513x over previous
//
#include <hip/hip_runtime.h>

// Encoding layer. B=16, C=512, N=4096, K=32.
// v9: split enc into two single-purpose streaming kernels. Evidence: one-kernel
// variants (v0-v8) phase-alternate chip-wide (GEMM1 oversubscribes HBM 3:1,
// then softmax/GEMM2 leave it idle) -> 2.1 TB/s avg with all pipes <27%;
// reduce_kernel (single-purpose) streams 5.3 TB/s in the same harness.
//  - K1 w_kernel (1024 blk, 64 tok): x -> S -> softmax -> W bf16 [b][k][n]
//    (4 MB). Whole 128 KB/block intake = one 32-float4 register burst, zero
//    drains (launch_bounds(256,2) gives 256-VGPR cap; sched_barrier fence
//    stops load sinking - v8's spill came from the 84-VGPR cap of (256,3)).
//    4 lgkm-only barriers. v8's verified S-split/Sp-merge/softmax math.
//  - K2 gemm2_kernel (512 blk, 128 tok): W + x (L3-resident after K1),
//    ZERO barriers, zero LDS, 8-deep register ring, 40 MFMA, f32-cw epilogue,
//    32 MiB partials.
//  - reduce: v0's proven 6 us kernel.

#define B_ 16
#define C_ 512
#define N_ 4096
#define K_ 32

#define CHUNK1 64                   // K1 tokens per block
#define NCH1 (N_ / CHUNK1)          // 64
#define NBLK1 (B_ * NCH1)           // 1024
#define XCN 68                      // XC n-stride (u16): 136 B, 8B-aligned rows

#define CHUNK2 128                  // K2 tokens per block
#define NCH2 (N_ / CHUNK2)          // 32
#define NBLK2 (B_ * NCH2)           // 512

typedef __attribute__((ext_vector_type(8))) short short8;
typedef __attribute__((ext_vector_type(16))) float floatx16;

__device__ inline unsigned short f2bf(float f) {
    union { float f; unsigned u; } v; v.f = f;
    unsigned r = v.u + 0x7FFFu + ((v.u >> 16) & 1u);  // RNE
    return (unsigned short)(r >> 16);
}

// LDS-drain-only barrier: global loads (vmcnt) stay in flight across it.
__device__ inline void cbar() {
    __builtin_amdgcn_sched_barrier(0);
    asm volatile("s_waitcnt lgkmcnt(0)" ::: "memory");
    __builtin_amdgcn_s_barrier();
    __builtin_amdgcn_sched_barrier(0);
}

// ============================ K1: W = softmax(scale*||x-c||^2) ==============
__global__ __launch_bounds__(256, 2)
void w_kernel(const float* __restrict__ x,
              const float* __restrict__ cw,
              const float* __restrict__ scale,
              unsigned short* __restrict__ Wg)   // bf16 [B][K][N]
{
    __shared__ unsigned short XC[256 * XCN];     // one c-half bf16, 34816 B
    __shared__ float Sp[2][K_ * 32];             // half-1 S partials, 8192 B
    __shared__ float xsqL[16][CHUNK1];           // ||x_n||^2 partials, 4096 B
    __shared__ float csq[K_];
    __shared__ float scl[K_];

    const int tid  = threadIdx.x;
    const int wave = tid >> 6;
    const int lane = tid & 63;
    const int l31  = lane & 31;
    const int lh   = lane >> 5;
    const int half = wave >> 1;                  // c-half owned in GEMM1
    const int tile = wave & 1;                   // token-tile owned in GEMM1

    const int b     = blockIdx.x >> 6;           // NCH1 = 64
    const int chunk = blockIdx.x & (NCH1 - 1);
    const float* xb = x + (long)b * C_ * N_;

    // staging: thread = (r = tid>>4, p = tid&15); per burst 16 rows
    // (local row i*16+r), each one float4 (tokens p*4..p*4+3).
    const int r = tid >> 4;
    const int p = tid & 15;
    const float* xrow = xb + chunk * CHUNK1 + p * 4;

    float4 bufA[16], bufB[16];
#define BISSUE(buf_, cbase_)                                                   \
    { _Pragma("unroll")                                                        \
      for (int i = 0; i < 16; ++i)                                             \
          buf_[i] = *(const float4*)(xrow + (long)((cbase_) + i * 16 + r) * N_); }

    float xs0 = 0.f, xs1 = 0.f, xs2 = 0.f, xs3 = 0.f;
#define BWRITE(buf_)                                                           \
    { _Pragma("unroll")                                                        \
      for (int i = 0; i < 16; ++i) {                                           \
          const float4 v = buf_[i];                                            \
          xs0 += v.x * v.x; xs1 += v.y * v.y;                                  \
          xs2 += v.z * v.z; xs3 += v.w * v.w;                                  \
          const unsigned lo = (unsigned)f2bf(v.x) | ((unsigned)f2bf(v.y) << 16);\
          const unsigned hi = (unsigned)f2bf(v.z) | ((unsigned)f2bf(v.w) << 16);\
          *(uint2*)&XC[(i * 16 + r) * XCN + p * 4] = make_uint2(lo, hi);       \
      } }

    // A-fragments: f32 cw rows (L2-hot) converted in-register.
    const float* cwr = cw + l31 * C_ + lh * 8;
    short8 afA[4], afB[4];
#define AFLOADG(buf_, coff_)                                                   \
    { _Pragma("unroll")                                                        \
      for (int s = 0; s < 4; ++s) {                                            \
          const float4 u0 = *(const float4*)(cwr + (coff_) + s * 16);          \
          const float4 u1 = *(const float4*)(cwr + (coff_) + s * 16 + 4);      \
          short8 t_;                                                           \
          t_[0] = (short)f2bf(u0.x); t_[1] = (short)f2bf(u0.y);                \
          t_[2] = (short)f2bf(u0.z); t_[3] = (short)f2bf(u0.w);                \
          t_[4] = (short)f2bf(u1.x); t_[5] = (short)f2bf(u1.y);                \
          t_[6] = (short)f2bf(u1.z); t_[7] = (short)f2bf(u1.w);                \
          buf_[s] = t_; } }

#define G1STEP(afbuf_, lg_)                                                    \
    { _Pragma("unroll")                                                        \
      for (int s = 0; s < 4; ++s) {                                            \
          short8 bx;                                                           \
          _Pragma("unroll")                                                    \
          for (int j = 0; j < 8; ++j)                                          \
              bx[j] = (short)XC[((lg_) * 64 + s * 16 + lh * 8 + j) * XCN       \
                                + tile * 32 + l31];                            \
          S = __builtin_amdgcn_mfma_f32_32x32x16_bf16(afbuf_[s], bx, S, 0, 0, 0);\
      } }

    // ---- intake: the block's ENTIRE 128 KB x-slab in flight at once ----
    BISSUE(bufA, 0)
    if (tid < K_) scl[tid] = scale[tid];
    {
        const int k = tid >> 3, q = tid & 7;      // k row, 64-c slice
        const float4* src = (const float4*)(cw + k * C_ + q * 64);
        float ssum = 0.f;
        #pragma unroll
        for (int i = 0; i < 16; ++i) {
            const float4 v = src[i];
            ssum += v.x*v.x + v.y*v.y + v.z*v.z + v.w*v.w;
        }
        ssum += __shfl_xor(ssum, 1);
        ssum += __shfl_xor(ssum, 2);
        ssum += __shfl_xor(ssum, 4);
        if (q == 0) csq[k] = ssum;
    }
    AFLOADG(afA, half * 256)
    BISSUE(bufB, 256)
    __builtin_amdgcn_sched_barrier(0);   // pin: both bursts issued before drain

    BWRITE(bufA)                   // progressive vmcnt; bufB stays in flight
    cbar();                        // XC = c 0..255

    floatx16 S;
    #pragma unroll
    for (int i = 0; i < 16; ++i) S[i] = 0.f;

    if (half == 0) {               // GEMM1a: waves 0,1 on c 0..255
        AFLOADG(afB, 64)
        G1STEP(afA, 0)
        AFLOADG(afA, 128)
        G1STEP(afB, 1)
        AFLOADG(afB, 192)
        G1STEP(afA, 2)
        G1STEP(afB, 3)
    }
    cbar();                        // half-0 XC reads done

    BWRITE(bufB)                   // XC rows now c 256..511
    xsqL[r][p * 4 + 0] = xs0; xsqL[r][p * 4 + 1] = xs1;
    xsqL[r][p * 4 + 2] = xs2; xsqL[r][p * 4 + 3] = xs3;
    cbar();                        // XC half-B + xsqL ready

    if (half == 1) {               // GEMM1b: waves 2,3 on c 256..511
        AFLOADG(afB, 256 + 64)
        G1STEP(afA, 0)
        AFLOADG(afA, 256 + 128)
        G1STEP(afB, 1)
        AFLOADG(afB, 256 + 192)
        G1STEP(afA, 2)
        G1STEP(afB, 3)
        #pragma unroll
        for (int rr = 0; rr < 16; ++rr)
            Sp[tile][((rr & 3) + 8 * (rr >> 2) + 4 * lh) * 32 + l31] = S[rr];
    }
    cbar();                        // Sp ready

    // ---- softmax (waves 0,1) + W store: token n = tile*32 + l31 ----
    if (half == 0) {
        const int n = tile * 32 + l31;
        float xq = 0.f;
        #pragma unroll
        for (int rr = 0; rr < 16; ++rr) xq += xsqL[rr][n];
        float L[16], mx = -3.4e38f;
        #pragma unroll
        for (int rr = 0; rr < 16; ++rr) {
            const int k = (rr & 3) + 8 * (rr >> 2) + 4 * lh;
            L[rr] = scl[k] * (xq - 2.f * (S[rr] + Sp[tile][k * 32 + l31]) + csq[k]);
            mx = fmaxf(mx, L[rr]);
        }
        mx = fmaxf(mx, __shfl_xor(mx, 32));
        float sum = 0.f;
        #pragma unroll
        for (int rr = 0; rr < 16; ++rr) { L[rr] = __expf(L[rr] - mx); sum += L[rr]; }
        sum += __shfl_xor(sum, 32);
        const float inv = 1.f / sum;
        #pragma unroll
        for (int rr = 0; rr < 16; ++rr) {
            const int k = (rr & 3) + 8 * (rr >> 2) + 4 * lh;
            Wg[(size_t)(b * K_ + k) * N_ + chunk * CHUNK1 + n] = f2bf(L[rr] * inv);
        }
    }
}

// ===================== K2: enc[k][c] partials = W @ x^T =====================
template <int USE_WS>
__global__ __launch_bounds__(256, 2)
void gemm2_kernel(const float* __restrict__ x,
                  const unsigned short* __restrict__ Wg,
                  const float* __restrict__ cw,
                  float* __restrict__ outp)
{
    const int tid  = threadIdx.x;
    const int wave = tid >> 6;
    const int lane = tid & 63;
    const int l31  = lane & 31;
    const int lh   = lane >> 5;

    const int b     = blockIdx.x >> 5;           // NCH2 = 32
    const int chunk = blockIdx.x & (NCH2 - 1);
    const float* xb = x + (long)b * C_ * N_;

    // A-frags: W bf16 [b][k][n], k = l31; contraction slice st -> n st*16+lh*8
    const unsigned short* wr = Wg + (size_t)(b * K_ + l31) * N_
                               + chunk * CHUNK2 + lh * 8;
    short8 aw[8];
    #pragma unroll
    for (int st = 0; st < 8; ++st)
        aw[st] = *(const short8*)(wr + st * 16);

    floatx16 wacc;
    #pragma unroll
    for (int i = 0; i < 16; ++i) wacc[i] = 0.f;
    {
        short8 ones;
        #pragma unroll
        for (int j = 0; j < 8; ++j) ones[j] = (short)0x3F80;
        #pragma unroll
        for (int st = 0; st < 8; ++st)
            wacc = __builtin_amdgcn_mfma_f32_32x32x16_bf16(aw[st], ones, wacc, 0, 0, 0);
    }

    // B: x rows (L3-resident after K1), 8-deep register ring, no barriers
    float4 bv[8][2];
#define G2LOAD(bi_, i_)                                                        \
    { const int t_ = (i_) >> 3, st_ = (i_) & 7;                                \
      const int c_ = wave * 128 + t_ * 32 + l31;                               \
      const int no_ = st_ * 16 + lh * 8;                                       \
      const float* p_ = xb + (long)c_ * N_ + chunk * CHUNK2 + no_;             \
      bv[bi_][0] = *(const float4*)p_;                                         \
      bv[bi_][1] = *(const float4*)(p_ + 4); }
    G2LOAD(0, 0) G2LOAD(1, 1) G2LOAD(2, 2) G2LOAD(3, 3)
    G2LOAD(4, 4) G2LOAD(5, 5) G2LOAD(6, 6) G2LOAD(7, 7)

    floatx16 acc[4];
    #pragma unroll
    for (int t = 0; t < 4; ++t)
        #pragma unroll
        for (int i = 0; i < 16; ++i) acc[t][i] = 0.f;

    #pragma unroll
    for (int i = 0; i < 32; ++i) {               // i = t*8 + st
        const int bi = i & 7;
        const int t  = i >> 3, st = i & 7;
        const float4 v0 = bv[bi][0];
        const float4 v1 = bv[bi][1];
        short8 bx;
        bx[0] = (short)f2bf(v0.x); bx[1] = (short)f2bf(v0.y);
        bx[2] = (short)f2bf(v0.z); bx[3] = (short)f2bf(v0.w);
        bx[4] = (short)f2bf(v1.x); bx[5] = (short)f2bf(v1.y);
        bx[6] = (short)f2bf(v1.z); bx[7] = (short)f2bf(v1.w);
        acc[t] = __builtin_amdgcn_mfma_f32_32x32x16_bf16(aw[st], bx, acc[t], 0, 0, 0);
        if (i + 8 < 32) G2LOAD(bi, i + 8)
    }

    // epilogue: val = acc - wsum[k]*cw[k][c] (f32 cw)
    float* dst = USE_WS ? (outp + (size_t)blockIdx.x * K_ * C_)
                        : (outp + (size_t)b * K_ * C_);
    #pragma unroll
    for (int t = 0; t < 4; ++t) {
        const int c = wave * 128 + t * 32 + l31;
        #pragma unroll
        for (int rr = 0; rr < 16; ++rr) {
            const int k = (rr & 3) + 8 * (rr >> 2) + 4 * lh;
            const float val = acc[t][rr] - wacc[rr] * cw[k * C_ + c];
            if (USE_WS) dst[k * C_ + c] = val;
            else        atomicAdd(dst + k * C_ + c, val);
        }
    }
}

// out[b][k][c] = sum_{ch<32} part[b*32+ch][k][c];  grid 256 x 256, float4
__global__ __launch_bounds__(256)
void reduce_kernel(const float4* __restrict__ part, float4* __restrict__ out)
{
    const int gid = blockIdx.x * 256 + threadIdx.x;   // 0..65535
    const int bb  = gid >> 12;                        // 4096 float4 per batch
    const int i4  = gid & 4095;
    const float4* pp = part + ((size_t)bb * NCH2) * 4096 + i4;
    float4 s = make_float4(0.f, 0.f, 0.f, 0.f);
    #pragma unroll
    for (int j = 0; j < NCH2; ++j) {
        const float4 v = pp[(size_t)j * 4096];
        s.x += v.x; s.y += v.y; s.z += v.z; s.w += v.w;
    }
    out[gid] = s;
}

extern "C" void kernel_launch(void* const* d_in, const int* in_sizes, int n_in,
                              void* d_out, int out_size, void* d_ws, size_t ws_size,
                              hipStream_t stream) {
    const float* x     = (const float*)d_in[0];
    const float* cw    = (const float*)d_in[1];
    const float* scale = (const float*)d_in[2];
    float* out = (float*)d_out;

    // ws layout: W bf16 [B][K][N] = 4 MiB at 0; partials at 4 MiB.
    unsigned short* Wg = (unsigned short*)d_ws;
    const size_t w_bytes  = (size_t)B_ * K_ * N_ * sizeof(unsigned short); // 4 MiB
    const size_t ws_full  = w_bytes + (size_t)NBLK2 * K_ * C_ * sizeof(float); // 36 MiB

    hipLaunchKernelGGL(w_kernel, dim3(NBLK1), dim3(256), 0, stream,
                       x, cw, scale, Wg);
    if (ws_size >= ws_full) {
        float* part = (float*)((char*)d_ws + w_bytes);
        hipLaunchKernelGGL(gemm2_kernel<1>, dim3(NBLK2), dim3(256), 0, stream,
                           x, Wg, cw, part);
        hipLaunchKernelGGL(reduce_kernel, dim3(256), dim3(256), 0, stream,
                           (const float4*)part, (float4*)out);
    } else {
        hipMemsetAsync(out, 0, (size_t)out_size * sizeof(float), stream);
        hipLaunchKernelGGL(gemm2_kernel<0>, dim3(NBLK2), dim3(256), 0, stream,
                           x, Wg, cw, out);
    }
}